// Round 8
// baseline (218.230 us; speedup 1.0000x reference)
//
#include <hip/hip_runtime.h>

// NCE loss, fused. N=16384 rows, E=512, V=50257, NR=100 shared noise words.
// loss = mean_rows[ softplus(-x_t) + sum_j softplus(x_nj) ],
//   x = <inp_row, emb_word> + bias_w - log V - logp_noise_w - log NR
//
// R8: coalesced LDS staging (kills the 16-line gathers).
//  - prep_noise: noise rows f32->bf16 once into d_ws ([kg][word][8]) + out=0.
//  - main: 1024 blocks x 256 thr, 16 rows/block, 4-way K-split. Per K-chunk
//    of 256: all 256 threads stage A (inp rows) and T (emb[target] rows) into
//    LDS with COALESCED dwordx4 loads (thread = 16 consecutive floats of one
//    row; 8 contiguous 128B lines per wave-instr vs 16 scattered before),
//    convert to bf16, then waves read MFMA fragments via ds_read_b128.
//    K-split combine via 8KB LDS ds_add (was 32KB slabs) -> ~25.7KB LDS,
//    6 blocks/CU; VGPR ~80 -> up to 24 waves/CU.

#define E_SZ   512
#define NROWS  16384
#define NRn    100
#define NWp    112
#define MT     16
#define NBLK   (NROWS / MT)
#define SASTR  264        // staged-tile stride in bf16 (256 + 8 pad)

typedef __attribute__((ext_vector_type(8))) short short8;
typedef __attribute__((ext_vector_type(4))) float f32x4;

#define NTL 15.430077572997398f   // log(V) + log(NR)

__device__ __forceinline__ unsigned int pack2(float a, float b) {
    unsigned int ua = __float_as_uint(a) + 0x8000u;
    unsigned int ub = __float_as_uint(b) + 0x8000u;
    return __builtin_amdgcn_perm(ub, ua, 0x07060302u); // [ua.b2,ua.b3,ub.b2,ub.b3]
}
__device__ __forceinline__ float softplus(float x) {
    return fmaxf(x, 0.f) + log1pf(__expf(-fabsf(x)));
}
__device__ __forceinline__ short8 cvt8(float4 x0, float4 x1) {
    union { unsigned int u[4]; short8 s; } r;
    r.u[0] = pack2(x0.x, x0.y);
    r.u[1] = pack2(x0.z, x0.w);
    r.u[2] = pack2(x1.x, x1.y);
    r.u[3] = pack2(x1.z, x1.w);
    return r.s;
}

// ---- kernel 1: noise rows f32 -> bf16 (nB[kg][word][8], kg=k>>3) + out=0 ----
__global__ __launch_bounds__(128)
void prep_noise(const float* __restrict__ emb, const float* __restrict__ bias,
                const float* __restrict__ lpn, const int* __restrict__ nidx,
                unsigned short* __restrict__ nB,   // (64, 112, 8) bf16
                float* __restrict__ nBn,           // (112,)
                float* __restrict__ out)
{
    const int j = blockIdx.x;          // word slot 0..111
    const int t = threadIdx.x;         // 0..127, elems 4t..4t+3
    const int idx = (j < NRn) ? nidx[j] : 0;
    float4 v = {0.f, 0.f, 0.f, 0.f};
    if (j < NRn) v = *(const float4*)(emb + (size_t)idx * E_SZ + t * 4);
    unsigned int u0 = pack2(v.x, v.y);
    unsigned int u1 = pack2(v.z, v.w);
    const int kg  = t >> 1;            // (4t)>>3
    const int off = (t & 1) * 4;       // (4t)&7
    *(uint2*)(nB + ((size_t)kg * NWp + j) * 8 + off) = make_uint2(u0, u1);
    if (t == 0)
        nBn[j] = (j < NRn) ? (bias[idx] - NTL - lpn[idx]) : 0.f;
    if (j == 0 && t == 0)
        out[0] = 0.f;                  // memset folded in; main kernel ordered after
}

// ---- kernel 2: fused scores + softplus + reduction ----
__global__ __launch_bounds__(256, 5)
void nce_loss_kernel(const float* __restrict__ inp,   // (N, E)
                     const float* __restrict__ emb,   // (V, E)
                     const float* __restrict__ bias,  // (V,)
                     const float* __restrict__ lpn,   // (V,)
                     const int*   __restrict__ target,// (N,)
                     const unsigned short* __restrict__ nB,  // (64,112,8) bf16
                     const float* __restrict__ nBn,   // (112,)
                     float* __restrict__ out)
{
    const int t    = threadIdx.x;
    const int w    = t >> 6;
    const int lane = t & 63;
    const int c    = lane & 15;
    const int q    = lane >> 4;
    const int r0   = blockIdx.x * MT;

    __shared__ __align__(16) unsigned short sA[MT * SASTR];  // 8448 B
    __shared__ __align__(16) unsigned short sT[MT * SASTR];  // 8448 B
    __shared__ float sAccS[2048];      // 8 KB shared accumulator (ds_add)
    __shared__ float sBn[NWp];
    __shared__ float sTb[MT];
    __shared__ int   sTg[MT];
    __shared__ float sWs[4];

    for (int i = t; i < 2048; i += 256) sAccS[i] = 0.f;
    if (t < NWp) sBn[t] = nBn[t];
    if (t < MT) {
        int tg = target[r0 + t];
        sTg[t] = tg;
        sTb[t] = bias[tg] - NTL - lpn[tg];
    }
    __syncthreads();

    // staging assignment: thread = (row, 16-float segment), fully coalesced
    const int srow = t >> 4;           // 0..15
    const int sseg = t & 15;           // 0..15
    const float* gA = inp + (size_t)(r0 + srow) * E_SZ + sseg * 16;
    const float* gT = emb + (size_t)sTg[srow] * E_SZ + sseg * 16;
    unsigned short* wA = sA + srow * SASTR + sseg * 16;
    unsigned short* wT = sT + srow * SASTR + sseg * 16;

    f32x4 accN[7];
    f32x4 accT = {0.f, 0.f, 0.f, 0.f};
#pragma unroll
    for (int ti = 0; ti < 7; ++ti) accN[ti] = {0.f, 0.f, 0.f, 0.f};

#pragma unroll 1
    for (int ck = 0; ck < 2; ++ck) {
        // ---- stage A/T K-chunk of 256 (8 coalesced dwordx4, deep MLP) ----
        {
            float4 a0 = *(const float4*)(gA + ck * 256);
            float4 a1 = *(const float4*)(gA + ck * 256 + 4);
            float4 a2 = *(const float4*)(gA + ck * 256 + 8);
            float4 a3 = *(const float4*)(gA + ck * 256 + 12);
            float4 t0 = *(const float4*)(gT + ck * 256);
            float4 t1 = *(const float4*)(gT + ck * 256 + 4);
            float4 t2 = *(const float4*)(gT + ck * 256 + 8);
            float4 t3 = *(const float4*)(gT + ck * 256 + 12);
            *(short8*)(wA)     = cvt8(a0, a1);
            *(short8*)(wA + 8) = cvt8(a2, a3);
            *(short8*)(wT)     = cvt8(t0, t1);
            *(short8*)(wT + 8) = cvt8(t2, t3);
        }
        __syncthreads();

        // ---- MFMA: wave w covers chunk-k [w*64, w*64+64) = 2 steps of 32 ----
#pragma unroll
        for (int ks = 0; ks < 2; ++ks) {
            const int ko = w * 64 + ks * 32 + q * 8;
            const unsigned short* pBk =
                nB + ((size_t)(ck * 32 + w * 8 + ks * 4 + q) * NWp + c) * 8;
            short8 Bv[7];
#pragma unroll
            for (int ti = 0; ti < 7; ++ti) Bv[ti] = *(const short8*)(pBk + ti * 128);
            short8 A = *(const short8*)&sA[c * SASTR + ko];
            short8 T = *(const short8*)&sT[c * SASTR + ko];
            accT = __builtin_amdgcn_mfma_f32_16x16x32_bf16(A, T, accT, 0, 0, 0);
#pragma unroll
            for (int ti = 0; ti < 7; ++ti)
                accN[ti] = __builtin_amdgcn_mfma_f32_16x16x32_bf16(A, Bv[ti], accN[ti], 0, 0, 0);
        }
        __syncthreads();   // LDS reuse hazard for next chunk
    }

    // ---- combine k-split partials: LDS float atomics (ds_add_f32) ----
#pragma unroll
    for (int ti = 0; ti < 7; ++ti)
#pragma unroll
        for (int r = 0; r < 4; ++r)
            atomicAdd(&sAccS[ti * 256 + r * 64 + lane], accN[ti][r]);
#pragma unroll
    for (int r = 0; r < 4; ++r)
        atomicAdd(&sAccS[7 * 256 + r * 64 + lane], accT[r]);
    __syncthreads();

    // ---- epilogue: slot = tile*256 + reg*64 + lane; C/D: col=lane&15,
    //      row=(lane>>4)*4+reg. Thread t reads slot i*256+t (reg = t>>6 = w).
    const int col  = lane & 15;
    const int erow = (lane >> 4) * 4 + w;
    float ll = 0.f;
#pragma unroll
    for (int i = 0; i < 7; ++i) {
        float v = sAccS[i * 256 + t];
        int word = i * 16 + col;
        if (word < NRn)
            ll += softplus(v + sBn[word]);
    }
    {
        float v = sAccS[7 * 256 + t];
        if (col == erow)
            ll += softplus(-(v + sTb[erow]));
    }

#pragma unroll
    for (int off = 32; off > 0; off >>= 1) ll += __shfl_down(ll, off);
    if (lane == 0) sWs[w] = ll;
    __syncthreads();
    if (t == 0) {
        float s = (sWs[0] + sWs[1]) + (sWs[2] + sWs[3]);
        atomicAdd(out, s * (1.f / (float)NROWS));
    }
}

extern "C" void kernel_launch(void* const* d_in, const int* in_sizes, int n_in,
                              void* d_out, int out_size, void* d_ws, size_t ws_size,
                              hipStream_t stream) {
    const float* inp    = (const float*)d_in[0];
    const float* emb    = (const float*)d_in[1];
    const float* bias   = (const float*)d_in[2];
    const float* lpn    = (const float*)d_in[3];
    const int*   target = (const int*)d_in[4];
    const int*   nidx   = (const int*)d_in[5];
    float* out = (float*)d_out;

    unsigned short* nB  = (unsigned short*)d_ws;              // 64*112*8*2 = 114688 B
    float*          nBn = (float*)((char*)d_ws + (size_t)64 * NWp * 8 * 2);

    prep_noise<<<NWp, 128, 0, stream>>>(emb, bias, lpn, nidx, nB, nBn, out);
    nce_loss_kernel<<<NBLK, 256, 0, stream>>>(inp, emb, bias, lpn, target, nB, nBn, out);
}